// Round 13
// baseline (540.598 us; speedup 1.0000x reference)
//
#include <hip/hip_runtime.h>

#define B_  16
#define L_  1024
#define E_  256
#define H_  8
#define DH_ 32
#define M_  (B_ * L_)                 // 16384 rows
#define SCALE_L2E 0.25501817656f      // (1/sqrt(32)) * log2(e)

typedef unsigned short u16;
typedef unsigned int   u32;
typedef short bf8_t __attribute__((ext_vector_type(8)));   // 8 bf16 (4 VGPRs)
typedef float f4_t  __attribute__((ext_vector_type(4)));   // MFMA acc
union F4U { uint4 u; bf8_t s; };

static __device__ __forceinline__ float bf2f(u16 u) {
    return __uint_as_float(((u32)u) << 16);
}
static __device__ __forceinline__ u16 f2bf(float f) {
    u32 u = __float_as_uint(f);
    u32 r = 0x7FFFu + ((u >> 16) & 1u);   // RNE
    return (u16)((u + r) >> 16);
}
static __device__ __forceinline__ u32 pack2(float a, float b) {
    return (u32)f2bf(a) | ((u32)f2bf(b) << 16);
}
// truncated bf16 pair pack: 2 VALU ops (P values only; psum stays exact fp32)
static __device__ __forceinline__ u32 pack2t(float a, float b) {
    return (__float_as_uint(a) >> 16) | (__float_as_uint(b) & 0xFFFF0000u);
}

// ---- kernel 1: embedding gather + LN (wave-per-row); low blocks convert W->bf16
__global__ __launch_bounds__(256) void embed_conv_k(
    const int* __restrict__ seq,
    const float* __restrict__ emb_w,      // [L,E,4] fp32 (read as float4)
    const float* __restrict__ emb_b,      // [L,E]
    const float* __restrict__ in_proj_w,  // [768,256] fp32
    const float* __restrict__ out_w,      // [256,256] fp32
    u16* __restrict__ emb,                // [M,256] bf16
    u16* __restrict__ wcvt)               // [768*256 + 256*256] bf16 (wqkv|wout)
{
    int blk = blockIdx.x, tid = threadIdx.x;
    if (blk < 1024) {                      // 262144 weight elements
        int idx = blk * 256 + tid;
        float v = (idx < 196608) ? in_proj_w[idx] : out_w[idx - 196608];
        wcvt[idx] = f2bf(v);
    }
    int w = tid >> 6, lane = tid & 63;
    int bl = blk * 4 + w;                  // row in [0, M)
    int l = bl & (L_ - 1);
    int cls = seq[bl];
    const float4* wrow = (const float4*)emb_w + (size_t)l * 256;
    float4 bb = *(const float4*)(emb_b + (size_t)l * 256 + lane * 4);
    float bv[4] = {bb.x, bb.y, bb.z, bb.w};
    float x[4], s = 0.f, q = 0.f;
    #pragma unroll
    for (int j = 0; j < 4; ++j) {
        float4 w4 = wrow[lane * 4 + j];
        float t = ((cls == 0) ? w4.x : (cls == 1) ? w4.y : (cls == 2) ? w4.z : w4.w) + bv[j];
        x[j] = t; s += t; q += t * t;
    }
    #pragma unroll
    for (int off = 1; off < 64; off <<= 1) {
        s += __shfl_xor(s, off);
        q += __shfl_xor(q, off);
    }
    float mean = s * (1.0f / 256.0f);
    float var  = q * (1.0f / 256.0f) - mean * mean;
    float rstd = rsqrtf(var + 1e-5f);
    ushort4 o = { f2bf((x[0] - mean) * rstd), f2bf((x[1] - mean) * rstd),
                  f2bf((x[2] - mean) * rstd), f2bf((x[3] - mean) * rstd) };
    *(ushort4*)(emb + (size_t)bl * 256 + lane * 4) = o;
}

// ---- kernel 2: QKV = emb @ Wqkv^T + b (MFMA, LDS-free), 4 m-tiles per wave
// (B-frags reused 4x -> 8 loads feed 16 MFMAs per ks). Q/K: transposed C ->
// ushort4 stores into [bh][l][32]; V: normal C, stored transposed vt[bh][d][l].
__global__ __launch_bounds__(256) void gemm_qkv_mfma_k(
    const u16* __restrict__ emb,      // [M,256] bf16
    const u16* __restrict__ wqkv,     // [768,256] bf16
    const float* __restrict__ bias,   // [768] fp32
    u16* __restrict__ q_s, u16* __restrict__ k_s, u16* __restrict__ vt)
{
    int tid = threadIdx.x;
    int w = tid >> 6, lane = tid & 63, l15 = lane & 15, quad = lane >> 4;
    int n0 = blockIdx.x * 64, m0 = blockIdx.y * 256;
    int b = m0 >> 10;

    const u16* Ap = emb  + (size_t)(m0 + w * 64 + l15) * 256 + quad * 8;
    const u16* Bp = wqkv + (size_t)(n0 + l15) * 256 + quad * 8;

    f4_t acc[4][4] = {{{0,0,0,0},{0,0,0,0},{0,0,0,0},{0,0,0,0}},
                      {{0,0,0,0},{0,0,0,0},{0,0,0,0},{0,0,0,0}},
                      {{0,0,0,0},{0,0,0,0},{0,0,0,0},{0,0,0,0}},
                      {{0,0,0,0},{0,0,0,0},{0,0,0,0},{0,0,0,0}}};

    if (n0 < 512) {                        // ---- Q or K: transposed C ----
        #pragma unroll
        for (int ks = 0; ks < 8; ++ks) {
            F4U bfr[4];
            #pragma unroll
            for (int nc = 0; nc < 4; ++nc)
                bfr[nc].u = *(const uint4*)(Bp + nc * 16 * 256 + ks * 32);
            #pragma unroll
            for (int t = 0; t < 4; ++t) {
                F4U a; a.u = *(const uint4*)(Ap + t * 16 * 256 + ks * 32);
                #pragma unroll
                for (int nc = 0; nc < 4; ++nc)
                    acc[t][nc] = __builtin_amdgcn_mfma_f32_16x16x32_bf16(bfr[nc].s, a.s, acc[t][nc], 0, 0, 0);
            }
        }
        float sc = (n0 < 256) ? SCALE_L2E : 1.0f;
        u16* dst = (n0 < 256) ? q_s : k_s;
        #pragma unroll
        for (int t = 0; t < 4; ++t) {
            int l = (m0 & 1023) + w * 64 + t * 16 + l15;
            #pragma unroll
            for (int nc = 0; nc < 4; ++nc) {
                int nb = n0 + nc * 16 + quad * 4;  // 4 consecutive n = same head
                float4 b4 = *(const float4*)(bias + nb);
                int nl = nb & 255, h = nl >> 5, d0 = nl & 31;
                ushort4 o = { f2bf((acc[t][nc][0] + b4.x) * sc), f2bf((acc[t][nc][1] + b4.y) * sc),
                              f2bf((acc[t][nc][2] + b4.z) * sc), f2bf((acc[t][nc][3] + b4.w) * sc) };
                *(ushort4*)(dst + ((size_t)(b * 8 + h) * 1024 + l) * 32 + d0) = o;
            }
        }
    } else {                               // ---- V: normal C, store transposed ----
        #pragma unroll
        for (int ks = 0; ks < 8; ++ks) {
            F4U bfr[4];
            #pragma unroll
            for (int nc = 0; nc < 4; ++nc)
                bfr[nc].u = *(const uint4*)(Bp + nc * 16 * 256 + ks * 32);
            #pragma unroll
            for (int t = 0; t < 4; ++t) {
                F4U a; a.u = *(const uint4*)(Ap + t * 16 * 256 + ks * 32);
                #pragma unroll
                for (int nc = 0; nc < 4; ++nc)
                    acc[t][nc] = __builtin_amdgcn_mfma_f32_16x16x32_bf16(a.s, bfr[nc].s, acc[t][nc], 0, 0, 0);
            }
        }
        #pragma unroll
        for (int t = 0; t < 4; ++t) {
            int lq = (m0 & 1023) + w * 64 + t * 16 + quad * 4;
            #pragma unroll
            for (int nc = 0; nc < 4; ++nc) {
                int n = n0 + nc * 16 + l15;
                float bv = bias[n];
                int nl = n & 255, h = nl >> 5, d = nl & 31;
                ushort4 o = { f2bf(acc[t][nc][0] + bv), f2bf(acc[t][nc][1] + bv),
                              f2bf(acc[t][nc][2] + bv), f2bf(acc[t][nc][3] + bv) };
                *(ushort4*)(vt + ((size_t)(b * 8 + h) * 32 + d) * 1024 + lq) = o;
            }
        }
    }
}

// ---- kernel 3: MFMA flash attention. 64 q-rows per wave; FULLY UNROLLED
// K-loop (key0 compile-time -> loads become base+imm-offset, no per-iter
// address VALU). psum as float4 (no dependency chain). XCD-swizzled.
__global__ __launch_bounds__(256) void attn2_k(
    const u16* __restrict__ q_s,   // [bh][l][32] (pre-scaled by SCALE*log2e)
    const u16* __restrict__ k_s,   // [bh][l][32]
    const u16* __restrict__ vt,    // [bh][32][1024]
    u16* __restrict__ ctx)         // [bh][l][32]
{
    __shared__ u16 Ps[4][4][16 * 72];  // per-wave, per-tile P [q][key] (36 KB)
    int tid = threadIdx.x;
    int w = tid >> 6, lane = tid & 63, l15 = lane & 15, quad = lane >> 4;
    int g = blockIdx.x;                      // 512 blocks = 4 qt x 128 bh
    int bh = (g & 7) | ((g >> 5) << 3);      // XCD-local bh grouping
    int q0 = ((g >> 3) & 3) * 256 + w * 64;

    // base pointers with lane offsets folded in once
    const u16* kb0 = k_s + (size_t)bh * 1024 * 32 + (size_t)l15 * 32 + quad * 8;
    const u16* vb0 = vt  + (size_t)bh * 32 * 1024 + (size_t)l15 * 1024 + quad * 8;
    const u16* vb1 = vb0 + 16 * 1024;

    F4U qf[4];   // B-frags: lane holds Q[q=l15][d=quad*8+j] for 4 tiles
    #pragma unroll
    for (int t = 0; t < 4; ++t)
        qf[t].u = *(const uint4*)(q_s + ((size_t)bh * 1024 + q0 + t * 16 + l15) * 32 + quad * 8);

    f4_t O[4][2] = {{{0,0,0,0},{0,0,0,0}},{{0,0,0,0},{0,0,0,0}},
                    {{0,0,0,0},{0,0,0,0}},{{0,0,0,0},{0,0,0,0}}};
    f4_t psum4[4] = {{0,0,0,0},{0,0,0,0},{0,0,0,0},{0,0,0,0}};

    F4U kA[4], kB[4];

    #pragma unroll
    for (int nt = 0; nt < 4; ++nt)
        kA[nt].u = *(const uint4*)(kb0 + (size_t)(nt * 16) * 32);

    #pragma unroll
    for (int c = 0; c < 16; c += 2) {
        // prefetch next chunk's K (compile-time offsets)
        #pragma unroll
        for (int nt = 0; nt < 4; ++nt)
            kB[nt].u = *(const uint4*)(kb0 + (size_t)((c + 1) * 64 + nt * 16) * 32);

        // ---- STEP A (keys c*64 .. +63) ----
        {
            const int key0 = c * 64;
            F4U v[4];
            v[0].u = *(const uint4*)(vb0 + key0);
            v[1].u = *(const uint4*)(vb1 + key0);
            v[2].u = *(const uint4*)(vb0 + key0 + 32);
            v[3].u = *(const uint4*)(vb1 + key0 + 32);
            #pragma unroll
            for (int t = 0; t < 4; ++t) {
                f4_t s[4];
                #pragma unroll
                for (int nt = 0; nt < 4; ++nt) {
                    f4_t z = {0,0,0,0};
                    s[nt] = __builtin_amdgcn_mfma_f32_16x16x32_bf16(kA[nt].s, qf[t].s, z, 0, 0, 0);
                }
                u16* psw = Ps[w][t];
                #pragma unroll
                for (int nt = 0; nt < 4; ++nt) {
                    float p0 = exp2f(s[nt][0]), p1 = exp2f(s[nt][1]);
                    float p2 = exp2f(s[nt][2]), p3 = exp2f(s[nt][3]);
                    psum4[t][0] += p0; psum4[t][1] += p1;
                    psum4[t][2] += p2; psum4[t][3] += p3;
                    uint2 pk = { pack2t(p0, p1), pack2t(p2, p3) };
                    *(uint2*)(psw + l15 * 72 + nt * 16 + quad * 4) = pk;
                }
            }
            #pragma unroll
            for (int t = 0; t < 4; ++t) {
                u16* psw = Ps[w][t];
                #pragma unroll
                for (int k2 = 0; k2 < 2; ++k2) {
                    F4U pf; pf.u = *(const uint4*)(psw + l15 * 72 + k2 * 32 + quad * 8);
                    O[t][0] = __builtin_amdgcn_mfma_f32_16x16x32_bf16(v[k2 * 2 + 0].s, pf.s, O[t][0], 0, 0, 0);
                    O[t][1] = __builtin_amdgcn_mfma_f32_16x16x32_bf16(v[k2 * 2 + 1].s, pf.s, O[t][1], 0, 0, 0);
                }
            }
        }

        // prefetch chunk c+2's K
        if (c + 2 < 16) {
            #pragma unroll
            for (int nt = 0; nt < 4; ++nt)
                kA[nt].u = *(const uint4*)(kb0 + (size_t)((c + 2) * 64 + nt * 16) * 32);
        }

        // ---- STEP B (keys (c+1)*64 .. +63) ----
        {
            const int key0 = (c + 1) * 64;
            F4U v[4];
            v[0].u = *(const uint4*)(vb0 + key0);
            v[1].u = *(const uint4*)(vb1 + key0);
            v[2].u = *(const uint4*)(vb0 + key0 + 32);
            v[3].u = *(const uint4*)(vb1 + key0 + 32);
            #pragma unroll
            for (int t = 0; t < 4; ++t) {
                f4_t s[4];
                #pragma unroll
                for (int nt = 0; nt < 4; ++nt) {
                    f4_t z = {0,0,0,0};
                    s[nt] = __builtin_amdgcn_mfma_f32_16x16x32_bf16(kB[nt].s, qf[t].s, z, 0, 0, 0);
                }
                u16* psw = Ps[w][t];
                #pragma unroll
                for (int nt = 0; nt < 4; ++nt) {
                    float p0 = exp2f(s[nt][0]), p1 = exp2f(s[nt][1]);
                    float p2 = exp2f(s[nt][2]), p3 = exp2f(s[nt][3]);
                    psum4[t][0] += p0; psum4[t][1] += p1;
                    psum4[t][2] += p2; psum4[t][3] += p3;
                    uint2 pk = { pack2t(p0, p1), pack2t(p2, p3) };
                    *(uint2*)(psw + l15 * 72 + nt * 16 + quad * 4) = pk;
                }
            }
            #pragma unroll
            for (int t = 0; t < 4; ++t) {
                u16* psw = Ps[w][t];
                #pragma unroll
                for (int k2 = 0; k2 < 2; ++k2) {
                    F4U pf; pf.u = *(const uint4*)(psw + l15 * 72 + k2 * 32 + quad * 8);
                    O[t][0] = __builtin_amdgcn_mfma_f32_16x16x32_bf16(v[k2 * 2 + 0].s, pf.s, O[t][0], 0, 0, 0);
                    O[t][1] = __builtin_amdgcn_mfma_f32_16x16x32_bf16(v[k2 * 2 + 1].s, pf.s, O[t][1], 0, 0, 0);
                }
            }
        }
    }

    #pragma unroll
    for (int t = 0; t < 4; ++t) {
        float ps = (psum4[t][0] + psum4[t][1]) + (psum4[t][2] + psum4[t][3]);
        ps += __shfl_xor(ps, 16);
        ps += __shfl_xor(ps, 32);
        float inv = 1.0f / ps;
        // O C-layout is [d=quad*4+r][q=l15]: pack 4 d's -> 8B stores
        u16* op = ctx + ((size_t)bh * 1024 + q0 + t * 16 + l15) * 32;
        uint2 s0, s1;
        s0.x = pack2(O[t][0][0] * inv, O[t][0][1] * inv);
        s0.y = pack2(O[t][0][2] * inv, O[t][0][3] * inv);
        s1.x = pack2(O[t][1][0] * inv, O[t][1][1] * inv);
        s1.y = pack2(O[t][1][2] * inv, O[t][1][3] * inv);
        *(uint2*)(op + quad * 4)      = s0;
        *(uint2*)(op + 16 + quad * 4) = s1;
    }
}

// ---- kernel 4: out = LN(ctx @ Wout^T + out_b + emb) -> fp32, fused.
// 256 blocks x 64 rows; wave (wr,wc): 2 row-tiles, cols wc*128 (8 nc frags
// shared across both tiles). LN = 2 shfl_xor + LDS exchange between halves.
__global__ __launch_bounds__(256) void proj_ln_k(
    const u16* __restrict__ ctx,      // [bh][l][32] bf16
    const u16* __restrict__ wout,     // [256,256] bf16
    const float* __restrict__ out_b,  // [256]
    const u16* __restrict__ emb,      // [M,256] bf16
    float* __restrict__ out)          // [M,256] fp32
{
    __shared__ float2 sm[4][2][16];   // [wr*2+t][wc][l15]
    int tid = threadIdx.x;
    int w = tid >> 6, lane = tid & 63, l15 = lane & 15, quad = lane >> 4;
    int wr = w >> 1, wc = w & 1;
    int m0 = blockIdx.x * 64;
    int b = m0 >> 10;

    const u16* Bp = wout + (size_t)(wc * 128 + l15) * 256 + quad * 8;

    f4_t acc[2][8];
    #pragma unroll
    for (int t = 0; t < 2; ++t)
        #pragma unroll
        for (int nc = 0; nc < 8; ++nc) acc[t][nc] = (f4_t){0,0,0,0};

    #pragma unroll
    for (int ks = 0; ks < 8; ++ks) {      // k = ks*32 + quad*8+j (head ks)
        F4U bfr[8];
        #pragma unroll
        for (int nc = 0; nc < 8; ++nc)
            bfr[nc].u = *(const uint4*)(Bp + (size_t)nc * 16 * 256 + ks * 32);
        #pragma unroll
        for (int t = 0; t < 2; ++t) {
            int lb = (m0 & 1023) + wr * 32 + t * 16 + l15;
            F4U a; a.u = *(const uint4*)(ctx + ((size_t)(b * 8 + ks) * 1024 + lb) * 32 + quad * 8);
            #pragma unroll
            for (int nc = 0; nc < 8; ++nc)
                acc[t][nc] = __builtin_amdgcn_mfma_f32_16x16x32_bf16(bfr[nc].s, a.s, acc[t][nc], 0, 0, 0);
        }
    }

    float sv[2], qv[2];
    #pragma unroll
    for (int t = 0; t < 2; ++t) {
        int row = m0 + wr * 32 + t * 16 + l15;
        float s = 0.f, q = 0.f;
        #pragma unroll
        for (int nc = 0; nc < 8; ++nc) {
            int nb = wc * 128 + nc * 16 + quad * 4;
            float4 bb = *(const float4*)(out_b + nb);
            ushort4 e4 = *(const ushort4*)(emb + (size_t)row * 256 + nb);
            acc[t][nc][0] += bb.x + bf2f(e4.x);
            acc[t][nc][1] += bb.y + bf2f(e4.y);
            acc[t][nc][2] += bb.z + bf2f(e4.z);
            acc[t][nc][3] += bb.w + bf2f(e4.w);
            #pragma unroll
            for (int r = 0; r < 4; ++r) { s += acc[t][nc][r]; q += acc[t][nc][r] * acc[t][nc][r]; }
        }
        s += __shfl_xor(s, 16);  q += __shfl_xor(q, 16);
        s += __shfl_xor(s, 32);  q += __shfl_xor(q, 32);
        sv[t] = s; qv[t] = q;
        if (quad == 0) sm[wr * 2 + t][wc][l15] = make_float2(s, q);
    }
    __syncthreads();
    #pragma unroll
    for (int t = 0; t < 2; ++t) {
        int row = m0 + wr * 32 + t * 16 + l15;
        float2 oth = sm[wr * 2 + t][1 - wc][l15];
        float s = sv[t] + oth.x, q = qv[t] + oth.y;
        float mean = s * (1.0f / 256.0f);
        float var  = q * (1.0f / 256.0f) - mean * mean;
        float rstd = rsqrtf(var + 1e-5f);
        #pragma unroll
        for (int nc = 0; nc < 8; ++nc) {
            float4 o = { (acc[t][nc][0] - mean) * rstd, (acc[t][nc][1] - mean) * rstd,
                         (acc[t][nc][2] - mean) * rstd, (acc[t][nc][3] - mean) * rstd };
            *(float4*)(out + (size_t)row * 256 + wc * 128 + nc * 16 + quad * 4) = o;
        }
    }
}

extern "C" void kernel_launch(void* const* d_in, const int* in_sizes, int n_in,
                              void* d_out, int out_size, void* d_ws, size_t ws_size,
                              hipStream_t stream) {
    const int*   seq       = (const int*)d_in[0];
    const float* emb_w     = (const float*)d_in[1];
    const float* emb_b     = (const float*)d_in[2];
    const float* in_proj_w = (const float*)d_in[3];
    const float* in_proj_b = (const float*)d_in[4];
    const float* out_w     = (const float*)d_in[5];
    const float* out_b     = (const float*)d_in[6];
    float*       out       = (float*)d_out;

    const size_t P = (size_t)M_ * 256;
    u16* ws   = (u16*)d_ws;
    u16* emb  = ws;                 //  8 MB [M,256]
    u16* q_s  = ws + P;             //  8 MB [bh][l][32]
    u16* k_s  = ws + 2 * P;         //  8 MB [bh][l][32]
    u16* vt   = ws + 3 * P;         //  8 MB [bh][32][1024]
    u16* ctx  = ws + 4 * P;         //  8 MB [bh][l][32]
    u16* wqkv = ws + 5 * P;         //  384 KB [768,256] bf16
    u16* wout = wqkv + 768 * 256;   //  128 KB [256,256] bf16

    embed_conv_k<<<M_ / 4, 256, 0, stream>>>(seq, emb_w, emb_b, in_proj_w, out_w, emb, wqkv);
    gemm_qkv_mfma_k<<<dim3(12, 64), 256, 0, stream>>>(emb, wqkv, in_proj_b, q_s, k_s, vt);
    attn2_k<<<512, 256, 0, stream>>>(q_s, k_s, vt, ctx);
    proj_ln_k<<<M_ / 64, 256, 0, stream>>>(ctx, wout, out_b, emb, out);
}

// Round 14
// 194.471 us; speedup vs baseline: 2.7798x; 2.7798x over previous
//
#include <hip/hip_runtime.h>

#define B_  16
#define L_  1024
#define E_  256
#define H_  8
#define DH_ 32
#define M_  (B_ * L_)                 // 16384 rows
#define SCALE_L2E 0.25501817656f      // (1/sqrt(32)) * log2(e)

typedef unsigned short u16;
typedef unsigned int   u32;
typedef short bf8_t __attribute__((ext_vector_type(8)));   // 8 bf16 (4 VGPRs)
typedef float f4_t  __attribute__((ext_vector_type(4)));   // MFMA acc
union F4U { uint4 u; bf8_t s; };

static __device__ __forceinline__ float bf2f(u16 u) {
    return __uint_as_float(((u32)u) << 16);
}
static __device__ __forceinline__ u16 f2bf(float f) {
    u32 u = __float_as_uint(f);
    u32 r = 0x7FFFu + ((u >> 16) & 1u);   // RNE
    return (u16)((u + r) >> 16);
}
static __device__ __forceinline__ u32 pack2(float a, float b) {
    return (u32)f2bf(a) | ((u32)f2bf(b) << 16);
}
// truncated bf16 pair pack: 2 VALU ops (P values only; psum stays exact fp32)
static __device__ __forceinline__ u32 pack2t(float a, float b) {
    return (__float_as_uint(a) >> 16) | (__float_as_uint(b) & 0xFFFF0000u);
}

// ---- kernel 1: embedding gather + LN (wave-per-row); low blocks convert W->bf16
__global__ __launch_bounds__(256) void embed_conv_k(
    const int* __restrict__ seq,
    const float* __restrict__ emb_w,      // [L,E,4] fp32 (read as float4)
    const float* __restrict__ emb_b,      // [L,E]
    const float* __restrict__ in_proj_w,  // [768,256] fp32
    const float* __restrict__ out_w,      // [256,256] fp32
    u16* __restrict__ emb,                // [M,256] bf16
    u16* __restrict__ wcvt)               // [768*256 + 256*256] bf16 (wqkv|wout)
{
    int blk = blockIdx.x, tid = threadIdx.x;
    if (blk < 1024) {                      // 262144 weight elements
        int idx = blk * 256 + tid;
        float v = (idx < 196608) ? in_proj_w[idx] : out_w[idx - 196608];
        wcvt[idx] = f2bf(v);
    }
    int w = tid >> 6, lane = tid & 63;
    int bl = blk * 4 + w;                  // row in [0, M)
    int l = bl & (L_ - 1);
    int cls = seq[bl];
    const float4* wrow = (const float4*)emb_w + (size_t)l * 256;
    float4 bb = *(const float4*)(emb_b + (size_t)l * 256 + lane * 4);
    float bv[4] = {bb.x, bb.y, bb.z, bb.w};
    float x[4], s = 0.f, q = 0.f;
    #pragma unroll
    for (int j = 0; j < 4; ++j) {
        float4 w4 = wrow[lane * 4 + j];
        float t = ((cls == 0) ? w4.x : (cls == 1) ? w4.y : (cls == 2) ? w4.z : w4.w) + bv[j];
        x[j] = t; s += t; q += t * t;
    }
    #pragma unroll
    for (int off = 1; off < 64; off <<= 1) {
        s += __shfl_xor(s, off);
        q += __shfl_xor(q, off);
    }
    float mean = s * (1.0f / 256.0f);
    float var  = q * (1.0f / 256.0f) - mean * mean;
    float rstd = rsqrtf(var + 1e-5f);
    ushort4 o = { f2bf((x[0] - mean) * rstd), f2bf((x[1] - mean) * rstd),
                  f2bf((x[2] - mean) * rstd), f2bf((x[3] - mean) * rstd) };
    *(ushort4*)(emb + (size_t)bl * 256 + lane * 4) = o;
}

// ---- kernel 2: QKV = emb @ Wqkv^T + b (MFMA, LDS-free), 4 m-tiles per wave
// (B-frags reused 4x -> 8 loads feed 16 MFMAs per ks). Q/K: transposed C ->
// ushort4 stores into [bh][l][32]; V: normal C, stored transposed vt[bh][d][l].
__global__ __launch_bounds__(256) void gemm_qkv_mfma_k(
    const u16* __restrict__ emb,      // [M,256] bf16
    const u16* __restrict__ wqkv,     // [768,256] bf16
    const float* __restrict__ bias,   // [768] fp32
    u16* __restrict__ q_s, u16* __restrict__ k_s, u16* __restrict__ vt)
{
    int tid = threadIdx.x;
    int w = tid >> 6, lane = tid & 63, l15 = lane & 15, quad = lane >> 4;
    int n0 = blockIdx.x * 64, m0 = blockIdx.y * 256;
    int b = m0 >> 10;

    const u16* Ap = emb  + (size_t)(m0 + w * 64 + l15) * 256 + quad * 8;
    const u16* Bp = wqkv + (size_t)(n0 + l15) * 256 + quad * 8;

    f4_t acc[4][4] = {{{0,0,0,0},{0,0,0,0},{0,0,0,0},{0,0,0,0}},
                      {{0,0,0,0},{0,0,0,0},{0,0,0,0},{0,0,0,0}},
                      {{0,0,0,0},{0,0,0,0},{0,0,0,0},{0,0,0,0}},
                      {{0,0,0,0},{0,0,0,0},{0,0,0,0},{0,0,0,0}}};

    if (n0 < 512) {                        // ---- Q or K: transposed C ----
        #pragma unroll
        for (int ks = 0; ks < 8; ++ks) {
            F4U bfr[4];
            #pragma unroll
            for (int nc = 0; nc < 4; ++nc)
                bfr[nc].u = *(const uint4*)(Bp + nc * 16 * 256 + ks * 32);
            #pragma unroll
            for (int t = 0; t < 4; ++t) {
                F4U a; a.u = *(const uint4*)(Ap + t * 16 * 256 + ks * 32);
                #pragma unroll
                for (int nc = 0; nc < 4; ++nc)
                    acc[t][nc] = __builtin_amdgcn_mfma_f32_16x16x32_bf16(bfr[nc].s, a.s, acc[t][nc], 0, 0, 0);
            }
        }
        float sc = (n0 < 256) ? SCALE_L2E : 1.0f;
        u16* dst = (n0 < 256) ? q_s : k_s;
        #pragma unroll
        for (int t = 0; t < 4; ++t) {
            int l = (m0 & 1023) + w * 64 + t * 16 + l15;
            #pragma unroll
            for (int nc = 0; nc < 4; ++nc) {
                int nb = n0 + nc * 16 + quad * 4;  // 4 consecutive n = same head
                float4 b4 = *(const float4*)(bias + nb);
                int nl = nb & 255, h = nl >> 5, d0 = nl & 31;
                ushort4 o = { f2bf((acc[t][nc][0] + b4.x) * sc), f2bf((acc[t][nc][1] + b4.y) * sc),
                              f2bf((acc[t][nc][2] + b4.z) * sc), f2bf((acc[t][nc][3] + b4.w) * sc) };
                *(ushort4*)(dst + ((size_t)(b * 8 + h) * 1024 + l) * 32 + d0) = o;
            }
        }
    } else {                               // ---- V: normal C, store transposed ----
        #pragma unroll
        for (int ks = 0; ks < 8; ++ks) {
            F4U bfr[4];
            #pragma unroll
            for (int nc = 0; nc < 4; ++nc)
                bfr[nc].u = *(const uint4*)(Bp + nc * 16 * 256 + ks * 32);
            #pragma unroll
            for (int t = 0; t < 4; ++t) {
                F4U a; a.u = *(const uint4*)(Ap + t * 16 * 256 + ks * 32);
                #pragma unroll
                for (int nc = 0; nc < 4; ++nc)
                    acc[t][nc] = __builtin_amdgcn_mfma_f32_16x16x32_bf16(a.s, bfr[nc].s, acc[t][nc], 0, 0, 0);
            }
        }
        #pragma unroll
        for (int t = 0; t < 4; ++t) {
            int lq = (m0 & 1023) + w * 64 + t * 16 + quad * 4;
            #pragma unroll
            for (int nc = 0; nc < 4; ++nc) {
                int n = n0 + nc * 16 + l15;
                float bv = bias[n];
                int nl = n & 255, h = nl >> 5, d = nl & 31;
                ushort4 o = { f2bf(acc[t][nc][0] + bv), f2bf(acc[t][nc][1] + bv),
                              f2bf(acc[t][nc][2] + bv), f2bf(acc[t][nc][3] + bv) };
                *(ushort4*)(vt + ((size_t)(b * 8 + h) * 32 + d) * 1024 + lq) = o;
            }
        }
    }
}

// ---- kernel 3: MFMA flash attention (R12 version — dynamic c-loop, low VGPR).
// 64 q-rows per wave (4 q-tiles share all K/V frags). XCD-swizzled: all 4
// blocks of a bh share g%8 (2 MB K/V per XCD L2). K ping-pong; fixed-max.
__global__ __launch_bounds__(256) void attn2_k(
    const u16* __restrict__ q_s,   // [bh][l][32] (pre-scaled by SCALE*log2e)
    const u16* __restrict__ k_s,   // [bh][l][32]
    const u16* __restrict__ vt,    // [bh][32][1024]
    u16* __restrict__ ctx)         // [bh][l][32]
{
    __shared__ u16 Ps[4][4][16 * 72];  // per-wave, per-tile P [q][key] (36 KB)
    int tid = threadIdx.x;
    int w = tid >> 6, lane = tid & 63, l15 = lane & 15, quad = lane >> 4;
    int g = blockIdx.x;                      // 512 blocks = 4 qt x 128 bh
    int bh = (g & 7) | ((g >> 5) << 3);      // XCD-local bh grouping
    int q0 = ((g >> 3) & 3) * 256 + w * 64;

    const u16* kb = k_s + (size_t)bh * 1024 * 32;
    const u16* vb = vt  + (size_t)bh * 32 * 1024;

    F4U qf[4];   // B-frags: lane holds Q[q=l15][d=quad*8+j] for 4 tiles
    #pragma unroll
    for (int t = 0; t < 4; ++t)
        qf[t].u = *(const uint4*)(q_s + ((size_t)bh * 1024 + q0 + t * 16 + l15) * 32 + quad * 8);

    f4_t O[4][2] = {{{0,0,0,0},{0,0,0,0}},{{0,0,0,0},{0,0,0,0}},
                    {{0,0,0,0},{0,0,0,0}},{{0,0,0,0},{0,0,0,0}}};
    float psum[4] = {0.f, 0.f, 0.f, 0.f};

    F4U kA[4], kB[4];

    auto LDK = [&](F4U* k, int key0) {
        #pragma unroll
        for (int nt = 0; nt < 4; ++nt)
            k[nt].u = *(const uint4*)(kb + (size_t)(key0 + nt * 16 + l15) * 32 + quad * 8);
    };
    auto STEP = [&](F4U* k, int key0) {
        F4U v[4];   // V loads first; consumed after all 4 tiles' softmax
        v[0].u = *(const uint4*)(vb + (size_t)l15 * 1024 + key0 + quad * 8);
        v[1].u = *(const uint4*)(vb + (size_t)(16 + l15) * 1024 + key0 + quad * 8);
        v[2].u = *(const uint4*)(vb + (size_t)l15 * 1024 + key0 + 32 + quad * 8);
        v[3].u = *(const uint4*)(vb + (size_t)(16 + l15) * 1024 + key0 + 32 + quad * 8);
        #pragma unroll
        for (int t = 0; t < 4; ++t) {
            f4_t s[4];
            #pragma unroll
            for (int nt = 0; nt < 4; ++nt) {
                f4_t z = {0,0,0,0};
                s[nt] = __builtin_amdgcn_mfma_f32_16x16x32_bf16(k[nt].s, qf[t].s, z, 0, 0, 0);
            }
            u16* psw = Ps[w][t];
            #pragma unroll
            for (int nt = 0; nt < 4; ++nt) {
                float p0 = exp2f(s[nt][0]), p1 = exp2f(s[nt][1]);
                float p2 = exp2f(s[nt][2]), p3 = exp2f(s[nt][3]);
                psum[t] += (p0 + p1) + (p2 + p3);
                uint2 pk = { pack2t(p0, p1), pack2t(p2, p3) };
                *(uint2*)(psw + l15 * 72 + nt * 16 + quad * 4) = pk;
            }
        }
        #pragma unroll
        for (int t = 0; t < 4; ++t) {
            u16* psw = Ps[w][t];
            #pragma unroll
            for (int k2 = 0; k2 < 2; ++k2) {
                F4U pf; pf.u = *(const uint4*)(psw + l15 * 72 + k2 * 32 + quad * 8);
                O[t][0] = __builtin_amdgcn_mfma_f32_16x16x32_bf16(v[k2 * 2 + 0].s, pf.s, O[t][0], 0, 0, 0);
                O[t][1] = __builtin_amdgcn_mfma_f32_16x16x32_bf16(v[k2 * 2 + 1].s, pf.s, O[t][1], 0, 0, 0);
            }
        }
    };

    LDK(kA, 0);
    for (int c = 0; c < 16; c += 2) {
        LDK(kB, (c + 1) * 64);
        STEP(kA, c * 64);
        if (c + 2 < 16) LDK(kA, (c + 2) * 64);
        STEP(kB, (c + 1) * 64);
    }

    #pragma unroll
    for (int t = 0; t < 4; ++t) {
        float ps = psum[t];
        ps += __shfl_xor(ps, 16);
        ps += __shfl_xor(ps, 32);
        float inv = 1.0f / ps;
        // O C-layout is [d=quad*4+r][q=l15]: pack 4 d's -> 8B stores
        u16* op = ctx + ((size_t)bh * 1024 + q0 + t * 16 + l15) * 32;
        uint2 s0, s1;
        s0.x = pack2(O[t][0][0] * inv, O[t][0][1] * inv);
        s0.y = pack2(O[t][0][2] * inv, O[t][0][3] * inv);
        s1.x = pack2(O[t][1][0] * inv, O[t][1][1] * inv);
        s1.y = pack2(O[t][1][2] * inv, O[t][1][3] * inv);
        *(uint2*)(op + quad * 4)      = s0;
        *(uint2*)(op + 16 + quad * 4) = s1;
    }
}

// ---- kernel 4: out = LN(ctx @ Wout^T + out_b + emb) -> fp32, fused.
// 1024 blocks x 16 rows (4 blocks/CU, 16 waves/CU for latency hiding).
// Wave w covers cols w*64..+63 (4 nc frags, acc=16 VGPR). Transposed C:
// lane owns row=l15, 16 cols. LN = 2 shfl_xor + 4-wave LDS exchange.
__global__ __launch_bounds__(256) void proj_ln_k(
    const u16* __restrict__ ctx,      // [bh][l][32] bf16
    const u16* __restrict__ wout,     // [256,256] bf16
    const float* __restrict__ out_b,  // [256]
    const u16* __restrict__ emb,      // [M,256] bf16
    float* __restrict__ out)          // [M,256] fp32
{
    __shared__ float2 sm[4][16];      // [wave][l15(row)]
    int tid = threadIdx.x;
    int w = tid >> 6, lane = tid & 63, l15 = lane & 15, quad = lane >> 4;
    int m0 = blockIdx.x * 16;
    int b = m0 >> 10, lbase = (m0 & 1023) + l15;

    const u16* Bp = wout + (size_t)(w * 64 + l15) * 256 + quad * 8;

    f4_t acc[4] = {{0,0,0,0},{0,0,0,0},{0,0,0,0},{0,0,0,0}};

    #pragma unroll
    for (int ks = 0; ks < 8; ++ks) {      // k = ks*32 + quad*8+j (head ks)
        F4U a; a.u = *(const uint4*)(ctx + ((size_t)(b * 8 + ks) * 1024 + lbase) * 32 + quad * 8);
        #pragma unroll
        for (int nc = 0; nc < 4; ++nc) {
            F4U bf; bf.u = *(const uint4*)(Bp + (size_t)nc * 16 * 256 + ks * 32);
            acc[nc] = __builtin_amdgcn_mfma_f32_16x16x32_bf16(bf.s, a.s, acc[nc], 0, 0, 0);
        }
    }

    int row = m0 + l15;
    float s = 0.f, q = 0.f;
    #pragma unroll
    for (int nc = 0; nc < 4; ++nc) {
        int nb = w * 64 + nc * 16 + quad * 4;
        float4 bb = *(const float4*)(out_b + nb);
        ushort4 e4 = *(const ushort4*)(emb + (size_t)row * 256 + nb);
        acc[nc][0] += bb.x + bf2f(e4.x);
        acc[nc][1] += bb.y + bf2f(e4.y);
        acc[nc][2] += bb.z + bf2f(e4.z);
        acc[nc][3] += bb.w + bf2f(e4.w);
        #pragma unroll
        for (int r = 0; r < 4; ++r) { s += acc[nc][r]; q += acc[nc][r] * acc[nc][r]; }
    }
    s += __shfl_xor(s, 16);  q += __shfl_xor(q, 16);
    s += __shfl_xor(s, 32);  q += __shfl_xor(q, 32);
    if (quad == 0) sm[w][l15] = make_float2(s, q);
    __syncthreads();
    float2 t0 = sm[0][l15], t1 = sm[1][l15], t2 = sm[2][l15], t3 = sm[3][l15];
    s = (t0.x + t1.x) + (t2.x + t3.x);
    q = (t0.y + t1.y) + (t2.y + t3.y);
    float mean = s * (1.0f / 256.0f);
    float var  = q * (1.0f / 256.0f) - mean * mean;
    float rstd = rsqrtf(var + 1e-5f);
    #pragma unroll
    for (int nc = 0; nc < 4; ++nc) {
        float4 o = { (acc[nc][0] - mean) * rstd, (acc[nc][1] - mean) * rstd,
                     (acc[nc][2] - mean) * rstd, (acc[nc][3] - mean) * rstd };
        *(float4*)(out + (size_t)row * 256 + w * 64 + nc * 16 + quad * 4) = o;
    }
}

extern "C" void kernel_launch(void* const* d_in, const int* in_sizes, int n_in,
                              void* d_out, int out_size, void* d_ws, size_t ws_size,
                              hipStream_t stream) {
    const int*   seq       = (const int*)d_in[0];
    const float* emb_w     = (const float*)d_in[1];
    const float* emb_b     = (const float*)d_in[2];
    const float* in_proj_w = (const float*)d_in[3];
    const float* in_proj_b = (const float*)d_in[4];
    const float* out_w     = (const float*)d_in[5];
    const float* out_b     = (const float*)d_in[6];
    float*       out       = (float*)d_out;

    const size_t P = (size_t)M_ * 256;
    u16* ws   = (u16*)d_ws;
    u16* emb  = ws;                 //  8 MB [M,256]
    u16* q_s  = ws + P;             //  8 MB [bh][l][32]
    u16* k_s  = ws + 2 * P;         //  8 MB [bh][l][32]
    u16* vt   = ws + 3 * P;         //  8 MB [bh][32][1024]
    u16* ctx  = ws + 4 * P;         //  8 MB [bh][l][32]
    u16* wqkv = ws + 5 * P;         //  384 KB [768,256] bf16
    u16* wout = wqkv + 768 * 256;   //  128 KB [256,256] bf16

    embed_conv_k<<<M_ / 4, 256, 0, stream>>>(seq, emb_w, emb_b, in_proj_w, out_w, emb, wqkv);
    gemm_qkv_mfma_k<<<dim3(12, 64), 256, 0, stream>>>(emb, wqkv, in_proj_b, q_s, k_s, vt);
    attn2_k<<<512, 256, 0, stream>>>(q_s, k_s, vt, ctx);
    proj_ln_k<<<M_ / 16, 256, 0, stream>>>(ctx, wout, out_b, emb, out);
}

// Round 15
// 183.258 us; speedup vs baseline: 2.9499x; 1.0612x over previous
//
#include <hip/hip_runtime.h>

#define B_  16
#define L_  1024
#define E_  256
#define H_  8
#define DH_ 32
#define M_  (B_ * L_)                 // 16384 rows
#define SCALE_L2E 0.25501817656f      // (1/sqrt(32)) * log2(e)

typedef unsigned short u16;
typedef unsigned int   u32;
typedef short bf8_t __attribute__((ext_vector_type(8)));   // 8 bf16 (4 VGPRs)
typedef float f4_t  __attribute__((ext_vector_type(4)));   // MFMA acc
union F4U { uint4 u; bf8_t s; };

static __device__ __forceinline__ float bf2f(u16 u) {
    return __uint_as_float(((u32)u) << 16);
}
static __device__ __forceinline__ u16 f2bf(float f) {
    u32 u = __float_as_uint(f);
    u32 r = 0x7FFFu + ((u >> 16) & 1u);   // RNE
    return (u16)((u + r) >> 16);
}
static __device__ __forceinline__ u32 pack2(float a, float b) {
    return (u32)f2bf(a) | ((u32)f2bf(b) << 16);
}
// truncated bf16 pair pack: 2 VALU ops (P values only; psum stays exact fp32)
static __device__ __forceinline__ u32 pack2t(float a, float b) {
    return (__float_as_uint(a) >> 16) | (__float_as_uint(b) & 0xFFFF0000u);
}

// ---- kernel 1: LN'd embedding TABLE (l x class, 4096 rows) + W->bf16 convert.
// emb[b,l,:] == table[l, seq[b,l], :] -- only 4096 distinct rows exist.
__global__ __launch_bounds__(256) void table_conv_k(
    const float* __restrict__ emb_w,      // [L,E,4] fp32
    const float* __restrict__ emb_b,      // [L,E]
    const float* __restrict__ in_proj_w,  // [768,256] fp32
    const float* __restrict__ out_w,      // [256,256] fp32
    u16* __restrict__ tbl,                // [L,4,E] bf16 (LN'd)
    u16* __restrict__ wcvt)               // [768*256 + 256*256] bf16 (wqkv|wout)
{
    int blk = blockIdx.x, tid = threadIdx.x;
    {   // weight conversion: 1024 blocks x 256 = all 262144 elements
        int idx = blk * 256 + tid;
        float v = (idx < 196608) ? in_proj_w[idx] : out_w[idx - 196608];
        wcvt[idx] = f2bf(v);
    }
    int w = tid >> 6, lane = tid & 63;
    int l = blk, c = w;                    // wave w handles class c of row l
    const float* wp = emb_w + (size_t)l * 1024 + c;
    float4 bb = *(const float4*)(emb_b + (size_t)l * 256 + lane * 4);
    float bv[4] = {bb.x, bb.y, bb.z, bb.w};
    float x[4], s = 0.f, q = 0.f;
    #pragma unroll
    for (int j = 0; j < 4; ++j) {
        float t = wp[(lane * 4 + j) * 4] + bv[j];
        x[j] = t; s += t; q += t * t;
    }
    #pragma unroll
    for (int off = 1; off < 64; off <<= 1) {
        s += __shfl_xor(s, off);
        q += __shfl_xor(q, off);
    }
    float mean = s * (1.0f / 256.0f);
    float var  = q * (1.0f / 256.0f) - mean * mean;
    float rstd = rsqrtf(var + 1e-5f);
    ushort4 o = { f2bf((x[0] - mean) * rstd), f2bf((x[1] - mean) * rstd),
                  f2bf((x[2] - mean) * rstd), f2bf((x[3] - mean) * rstd) };
    *(ushort4*)(tbl + ((size_t)l * 4 + c) * 256 + lane * 4) = o;
}

// ---- kernel 2: QKV = emb @ Wqkv^T + b (MFMA, LDS-free), 4 m-tiles per wave.
// A-rows read from the 2 MB LN'd table via seq indirection (L2-resident).
// Q/K: transposed C -> ushort4 stores into [bh][l][32]; V: stored vt[bh][d][l].
__global__ __launch_bounds__(256) void gemm_qkv_mfma_k(
    const int* __restrict__ seq,      // [M]
    const u16* __restrict__ tbl,      // [L,4,256] bf16
    const u16* __restrict__ wqkv,     // [768,256] bf16
    const float* __restrict__ bias,   // [768] fp32
    u16* __restrict__ q_s, u16* __restrict__ k_s, u16* __restrict__ vt)
{
    int tid = threadIdx.x;
    int w = tid >> 6, lane = tid & 63, l15 = lane & 15, quad = lane >> 4;
    int n0 = blockIdx.x * 64, m0 = blockIdx.y * 256;
    int b = m0 >> 10;

    const u16* Apt[4];
    #pragma unroll
    for (int t = 0; t < 4; ++t) {
        int m = m0 + w * 64 + t * 16 + l15;
        int cls = seq[m];
        Apt[t] = tbl + ((size_t)((m & 1023) * 4 + cls)) * 256 + quad * 8;
    }
    const u16* Bp = wqkv + (size_t)(n0 + l15) * 256 + quad * 8;

    f4_t acc[4][4] = {{{0,0,0,0},{0,0,0,0},{0,0,0,0},{0,0,0,0}},
                      {{0,0,0,0},{0,0,0,0},{0,0,0,0},{0,0,0,0}},
                      {{0,0,0,0},{0,0,0,0},{0,0,0,0},{0,0,0,0}},
                      {{0,0,0,0},{0,0,0,0},{0,0,0,0},{0,0,0,0}}};

    if (n0 < 512) {                        // ---- Q or K: transposed C ----
        #pragma unroll
        for (int ks = 0; ks < 8; ++ks) {
            F4U bfr[4];
            #pragma unroll
            for (int nc = 0; nc < 4; ++nc)
                bfr[nc].u = *(const uint4*)(Bp + nc * 16 * 256 + ks * 32);
            #pragma unroll
            for (int t = 0; t < 4; ++t) {
                F4U a; a.u = *(const uint4*)(Apt[t] + ks * 32);
                #pragma unroll
                for (int nc = 0; nc < 4; ++nc)
                    acc[t][nc] = __builtin_amdgcn_mfma_f32_16x16x32_bf16(bfr[nc].s, a.s, acc[t][nc], 0, 0, 0);
            }
        }
        float sc = (n0 < 256) ? SCALE_L2E : 1.0f;
        u16* dst = (n0 < 256) ? q_s : k_s;
        #pragma unroll
        for (int t = 0; t < 4; ++t) {
            int l = (m0 & 1023) + w * 64 + t * 16 + l15;
            #pragma unroll
            for (int nc = 0; nc < 4; ++nc) {
                int nb = n0 + nc * 16 + quad * 4;  // 4 consecutive n = same head
                float4 b4 = *(const float4*)(bias + nb);
                int nl = nb & 255, h = nl >> 5, d0 = nl & 31;
                ushort4 o = { f2bf((acc[t][nc][0] + b4.x) * sc), f2bf((acc[t][nc][1] + b4.y) * sc),
                              f2bf((acc[t][nc][2] + b4.z) * sc), f2bf((acc[t][nc][3] + b4.w) * sc) };
                *(ushort4*)(dst + ((size_t)(b * 8 + h) * 1024 + l) * 32 + d0) = o;
            }
        }
    } else {                               // ---- V: normal C, store transposed ----
        #pragma unroll
        for (int ks = 0; ks < 8; ++ks) {
            F4U bfr[4];
            #pragma unroll
            for (int nc = 0; nc < 4; ++nc)
                bfr[nc].u = *(const uint4*)(Bp + nc * 16 * 256 + ks * 32);
            #pragma unroll
            for (int t = 0; t < 4; ++t) {
                F4U a; a.u = *(const uint4*)(Apt[t] + ks * 32);
                #pragma unroll
                for (int nc = 0; nc < 4; ++nc)
                    acc[t][nc] = __builtin_amdgcn_mfma_f32_16x16x32_bf16(a.s, bfr[nc].s, acc[t][nc], 0, 0, 0);
            }
        }
        #pragma unroll
        for (int t = 0; t < 4; ++t) {
            int lq = (m0 & 1023) + w * 64 + t * 16 + quad * 4;
            #pragma unroll
            for (int nc = 0; nc < 4; ++nc) {
                int n = n0 + nc * 16 + l15;
                float bv = bias[n];
                int nl = n & 255, h = nl >> 5, d = nl & 31;
                ushort4 o = { f2bf(acc[t][nc][0] + bv), f2bf(acc[t][nc][1] + bv),
                              f2bf(acc[t][nc][2] + bv), f2bf(acc[t][nc][3] + bv) };
                *(ushort4*)(vt + ((size_t)(b * 8 + h) * 32 + d) * 1024 + lq) = o;
            }
        }
    }
}

// ---- kernel 3: MFMA flash attention (R12 structure — dynamic c-loop, 108 VGPR).
// 64 q-rows per wave (4 q-tiles share all K/V frags). XCD-swizzled: all 4
// blocks of a bh share g%8 (2 MB K/V per XCD L2). K ping-pong; fixed-max.
__global__ __launch_bounds__(256) void attn2_k(
    const u16* __restrict__ q_s,   // [bh][l][32] (pre-scaled by SCALE*log2e)
    const u16* __restrict__ k_s,   // [bh][l][32]
    const u16* __restrict__ vt,    // [bh][32][1024]
    u16* __restrict__ ctx)         // [bh][l][32]
{
    __shared__ u16 Ps[4][4][16 * 72];  // per-wave, per-tile P [q][key] (36 KB)
    int tid = threadIdx.x;
    int w = tid >> 6, lane = tid & 63, l15 = lane & 15, quad = lane >> 4;
    int g = blockIdx.x;                      // 512 blocks = 4 qt x 128 bh
    int bh = (g & 7) | ((g >> 5) << 3);      // XCD-local bh grouping
    int q0 = ((g >> 3) & 3) * 256 + w * 64;

    const u16* kb = k_s + (size_t)bh * 1024 * 32;
    const u16* vb = vt  + (size_t)bh * 32 * 1024;

    F4U qf[4];   // B-frags: lane holds Q[q=l15][d=quad*8+j] for 4 tiles
    #pragma unroll
    for (int t = 0; t < 4; ++t)
        qf[t].u = *(const uint4*)(q_s + ((size_t)bh * 1024 + q0 + t * 16 + l15) * 32 + quad * 8);

    f4_t O[4][2] = {{{0,0,0,0},{0,0,0,0}},{{0,0,0,0},{0,0,0,0}},
                    {{0,0,0,0},{0,0,0,0}},{{0,0,0,0},{0,0,0,0}}};
    float psum[4] = {0.f, 0.f, 0.f, 0.f};

    F4U kA[4], kB[4];

    auto LDK = [&](F4U* k, int key0) {
        #pragma unroll
        for (int nt = 0; nt < 4; ++nt)
            k[nt].u = *(const uint4*)(kb + (size_t)(key0 + nt * 16 + l15) * 32 + quad * 8);
    };
    auto STEP = [&](F4U* k, int key0) {
        F4U v[4];   // V loads first; consumed after all 4 tiles' softmax
        v[0].u = *(const uint4*)(vb + (size_t)l15 * 1024 + key0 + quad * 8);
        v[1].u = *(const uint4*)(vb + (size_t)(16 + l15) * 1024 + key0 + quad * 8);
        v[2].u = *(const uint4*)(vb + (size_t)l15 * 1024 + key0 + 32 + quad * 8);
        v[3].u = *(const uint4*)(vb + (size_t)(16 + l15) * 1024 + key0 + 32 + quad * 8);
        #pragma unroll
        for (int t = 0; t < 4; ++t) {
            f4_t s[4];
            #pragma unroll
            for (int nt = 0; nt < 4; ++nt) {
                f4_t z = {0,0,0,0};
                s[nt] = __builtin_amdgcn_mfma_f32_16x16x32_bf16(k[nt].s, qf[t].s, z, 0, 0, 0);
            }
            u16* psw = Ps[w][t];
            #pragma unroll
            for (int nt = 0; nt < 4; ++nt) {
                float p0 = exp2f(s[nt][0]), p1 = exp2f(s[nt][1]);
                float p2 = exp2f(s[nt][2]), p3 = exp2f(s[nt][3]);
                psum[t] += (p0 + p1) + (p2 + p3);
                uint2 pk = { pack2t(p0, p1), pack2t(p2, p3) };
                *(uint2*)(psw + l15 * 72 + nt * 16 + quad * 4) = pk;
            }
        }
        #pragma unroll
        for (int t = 0; t < 4; ++t) {
            u16* psw = Ps[w][t];
            #pragma unroll
            for (int k2 = 0; k2 < 2; ++k2) {
                F4U pf; pf.u = *(const uint4*)(psw + l15 * 72 + k2 * 32 + quad * 8);
                O[t][0] = __builtin_amdgcn_mfma_f32_16x16x32_bf16(v[k2 * 2 + 0].s, pf.s, O[t][0], 0, 0, 0);
                O[t][1] = __builtin_amdgcn_mfma_f32_16x16x32_bf16(v[k2 * 2 + 1].s, pf.s, O[t][1], 0, 0, 0);
            }
        }
    };

    LDK(kA, 0);
    for (int c = 0; c < 16; c += 2) {
        LDK(kB, (c + 1) * 64);
        STEP(kA, c * 64);
        if (c + 2 < 16) LDK(kA, (c + 2) * 64);
        STEP(kB, (c + 1) * 64);
    }

    #pragma unroll
    for (int t = 0; t < 4; ++t) {
        float ps = psum[t];
        ps += __shfl_xor(ps, 16);
        ps += __shfl_xor(ps, 32);
        float inv = 1.0f / ps;
        // O C-layout is [d=quad*4+r][q=l15]: pack 4 d's -> 8B stores
        u16* op = ctx + ((size_t)bh * 1024 + q0 + t * 16 + l15) * 32;
        uint2 s0, s1;
        s0.x = pack2(O[t][0][0] * inv, O[t][0][1] * inv);
        s0.y = pack2(O[t][0][2] * inv, O[t][0][3] * inv);
        s1.x = pack2(O[t][1][0] * inv, O[t][1][1] * inv);
        s1.y = pack2(O[t][1][2] * inv, O[t][1][3] * inv);
        *(uint2*)(op + quad * 4)      = s0;
        *(uint2*)(op + 16 + quad * 4) = s1;
    }
}

// ---- kernel 4: out = LN(ctx @ Wout^T + out_b + emb) -> fp32, fused.
// 1024 blocks x 16 rows (4 blocks/CU). Wave w covers cols w*64..+63.
// Residual read via seq-indirected table. LN = 2 shfl_xor + 4-wave LDS.
__global__ __launch_bounds__(256) void proj_ln_k(
    const int* __restrict__ seq,      // [M]
    const u16* __restrict__ ctx,      // [bh][l][32] bf16
    const u16* __restrict__ wout,     // [256,256] bf16
    const float* __restrict__ out_b,  // [256]
    const u16* __restrict__ tbl,      // [L,4,256] bf16
    float* __restrict__ out)          // [M,256] fp32
{
    __shared__ float2 sm[4][16];      // [wave][l15(row)]
    int tid = threadIdx.x;
    int w = tid >> 6, lane = tid & 63, l15 = lane & 15, quad = lane >> 4;
    int m0 = blockIdx.x * 16;
    int b = m0 >> 10, lbase = (m0 & 1023) + l15;

    const u16* Bp = wout + (size_t)(w * 64 + l15) * 256 + quad * 8;

    f4_t acc[4] = {{0,0,0,0},{0,0,0,0},{0,0,0,0},{0,0,0,0}};

    #pragma unroll
    for (int ks = 0; ks < 8; ++ks) {      // k = ks*32 + quad*8+j (head ks)
        F4U a; a.u = *(const uint4*)(ctx + ((size_t)(b * 8 + ks) * 1024 + lbase) * 32 + quad * 8);
        #pragma unroll
        for (int nc = 0; nc < 4; ++nc) {
            F4U bf; bf.u = *(const uint4*)(Bp + (size_t)nc * 16 * 256 + ks * 32);
            acc[nc] = __builtin_amdgcn_mfma_f32_16x16x32_bf16(bf.s, a.s, acc[nc], 0, 0, 0);
        }
    }

    int row = m0 + l15;
    int cls = seq[row];
    const u16* ep = tbl + ((size_t)((row & 1023) * 4 + cls)) * 256;
    float s = 0.f, q = 0.f;
    #pragma unroll
    for (int nc = 0; nc < 4; ++nc) {
        int nb = w * 64 + nc * 16 + quad * 4;
        float4 bb = *(const float4*)(out_b + nb);
        ushort4 e4 = *(const ushort4*)(ep + nb);
        acc[nc][0] += bb.x + bf2f(e4.x);
        acc[nc][1] += bb.y + bf2f(e4.y);
        acc[nc][2] += bb.z + bf2f(e4.z);
        acc[nc][3] += bb.w + bf2f(e4.w);
        #pragma unroll
        for (int r = 0; r < 4; ++r) { s += acc[nc][r]; q += acc[nc][r] * acc[nc][r]; }
    }
    s += __shfl_xor(s, 16);  q += __shfl_xor(q, 16);
    s += __shfl_xor(s, 32);  q += __shfl_xor(q, 32);
    if (quad == 0) sm[w][l15] = make_float2(s, q);
    __syncthreads();
    float2 t0 = sm[0][l15], t1 = sm[1][l15], t2 = sm[2][l15], t3 = sm[3][l15];
    s = (t0.x + t1.x) + (t2.x + t3.x);
    q = (t0.y + t1.y) + (t2.y + t3.y);
    float mean = s * (1.0f / 256.0f);
    float var  = q * (1.0f / 256.0f) - mean * mean;
    float rstd = rsqrtf(var + 1e-5f);
    #pragma unroll
    for (int nc = 0; nc < 4; ++nc) {
        float4 o = { (acc[nc][0] - mean) * rstd, (acc[nc][1] - mean) * rstd,
                     (acc[nc][2] - mean) * rstd, (acc[nc][3] - mean) * rstd };
        *(float4*)(out + (size_t)row * 256 + w * 64 + nc * 16 + quad * 4) = o;
    }
}

extern "C" void kernel_launch(void* const* d_in, const int* in_sizes, int n_in,
                              void* d_out, int out_size, void* d_ws, size_t ws_size,
                              hipStream_t stream) {
    const int*   seq       = (const int*)d_in[0];
    const float* emb_w     = (const float*)d_in[1];
    const float* emb_b     = (const float*)d_in[2];
    const float* in_proj_w = (const float*)d_in[3];
    const float* in_proj_b = (const float*)d_in[4];
    const float* out_w     = (const float*)d_in[5];
    const float* out_b     = (const float*)d_in[6];
    float*       out       = (float*)d_out;

    const size_t P   = (size_t)M_ * 256;     // 4,194,304 els
    const size_t TBL = (size_t)L_ * 4 * 256; // 1,048,576 els (2 MB)
    u16* ws   = (u16*)d_ws;
    u16* tbl  = ws;                  //  2 MB [L,4,256]
    u16* q_s  = ws + TBL;            //  8 MB [bh][l][32]
    u16* k_s  = q_s + P;             //  8 MB [bh][l][32]
    u16* vt   = k_s + P;             //  8 MB [bh][32][1024]
    u16* ctx  = vt + P;              //  8 MB [bh][l][32]
    u16* wqkv = ctx + P;             //  384 KB [768,256] bf16
    u16* wout = wqkv + 768 * 256;    //  128 KB [256,256] bf16

    table_conv_k<<<1024, 256, 0, stream>>>(emb_w, emb_b, in_proj_w, out_w, tbl, wqkv);
    gemm_qkv_mfma_k<<<dim3(12, 64), 256, 0, stream>>>(seq, tbl, wqkv, in_proj_b, q_s, k_s, vt);
    attn2_k<<<512, 256, 0, stream>>>(q_s, k_s, vt, ctx);
    proj_ln_k<<<M_ / 16, 256, 0, stream>>>(seq, ctx, wout, out_b, tbl, out);
}